// Round 1
// 4441.658 us; speedup vs baseline: 1.1747x; 1.1747x over previous
//
#include <hip/hip_runtime.h>
#include <stdint.h>

// Problem constants
#define B_ 32
#define T_ 2048
#define D_ 512
#define N_ 512
#define NG 2048   // 4 gates * N

typedef _Float16 f16;
typedef _Float16 half2v __attribute__((ext_vector_type(2)));
typedef _Float16 half8  __attribute__((ext_vector_type(8)));
typedef float    float4v __attribute__((ext_vector_type(4)));
typedef unsigned long long u64;

union U32H2 { unsigned u; half2v h; };
union U4H8  { uint4 u; half8 h; };

// ---------------- prep: cast x (f32) -> f16 ----------------
__global__ void prep_cast(const float* __restrict__ x, f16* __restrict__ x16) {
    long i = ((long)blockIdx.x * 256 + threadIdx.x) * 4;
    float4 v = *(const float4*)(x + i);
    union { f16 h[4]; uint2 u; } pk;
    pk.h[0] = (f16)v.x; pk.h[1] = (f16)v.y; pk.h[2] = (f16)v.z; pk.h[3] = (f16)v.w;
    *(uint2*)(x16 + i) = pk.u;
}

// ---------------- prep: transpose+cast weights, biases ----------------
__global__ void prep_w(const float* __restrict__ Wi, const float* __restrict__ Ui,
                       const float* __restrict__ Wf, const float* __restrict__ Uf,
                       const float* __restrict__ Wg, const float* __restrict__ Ug,
                       const float* __restrict__ Wc, const float* __restrict__ Uc,
                       const float* __restrict__ Wo,
                       const float* __restrict__ bi, const float* __restrict__ bff,
                       const float* __restrict__ bg, const float* __restrict__ bc,
                       f16* __restrict__ wt, f16* __restrict__ ut,
                       f16* __restrict__ wot, float* __restrict__ bias)
{
    const int y = blockIdx.y;
    const int e = blockIdx.x * 256 + threadIdx.x;   // 0..262143
    if (y < 4) {
        const float* src = (y == 0) ? Wi : (y == 1) ? Wf : (y == 2) ? Wg : Wc;
        int col = e >> 9, d = e & 511;
        wt[(long)y * 512 * 512 + e] = (f16)src[(long)d * 512 + col];   // wt[(g*512+col)][d]
    } else if (y < 8) {
        const float* src = (y == 4) ? Ui : (y == 5) ? Uf : (y == 6) ? Ug : Uc;
        int col = e >> 9, d = e & 511;
        ut[(long)(y - 4) * 512 * 512 + e] = (f16)src[(long)d * 512 + col];
    } else if (y == 8) {
        int col = e >> 9, d = e & 511;
        wot[e] = (f16)Wo[(long)d * 512 + col];
    } else {
        if (e < 2048) {
            const float* bsrc = (e < 512) ? bi : (e < 1024) ? bff : (e < 1536) ? bg : bc;
            bias[e] = bsrc[e & 511];
        }
    }
}

// ---------------- phase 1: xpre[b][t][2048] = x @ [Wi|Wf|Wg|Wc] + bias (f16 out) ----------------
__launch_bounds__(256)
__global__ void gemm_xw(const f16* __restrict__ A, const f16* __restrict__ Bt,
                        const float* __restrict__ bias, f16* __restrict__ C)
{
    __shared__ f16 sA[128 * 32];
    __shared__ f16 sB[128 * 32];
    const int tid = threadIdx.x;
    const int m0 = blockIdx.y * 128;
    const int n0 = blockIdx.x * 128;
    const int wave = tid >> 6, lane = tid & 63;
    const int wm = wave >> 1, wn = wave & 1;
    const int lrow = lane & 15, quad = lane >> 4;

    float4v acc[4][4];
#pragma unroll
    for (int i = 0; i < 4; i++)
#pragma unroll
        for (int j = 0; j < 4; j++) acc[i][j] = (float4v){0.f, 0.f, 0.f, 0.f};

    const int srow = tid >> 2;        // 0..63
    const int sk8 = (tid & 3) * 8;    // 0,8,16,24

    for (int k0 = 0; k0 < 512; k0 += 32) {
#pragma unroll
        for (int rr = 0; rr < 128; rr += 64) {
            const int row = rr + srow;
            *(uint4*)&sA[row * 32 + sk8] = *(const uint4*)&A[(long)(m0 + row) * 512 + k0 + sk8];
            *(uint4*)&sB[row * 32 + sk8] = *(const uint4*)&Bt[(long)(n0 + row) * 512 + k0 + sk8];
        }
        __syncthreads();
        half8 af[4], bf[4];
#pragma unroll
        for (int mi = 0; mi < 4; mi++)
            af[mi] = *(half8*)&sA[(wm * 64 + mi * 16 + lrow) * 32 + quad * 8];
#pragma unroll
        for (int ni = 0; ni < 4; ni++)
            bf[ni] = *(half8*)&sB[(wn * 64 + ni * 16 + lrow) * 32 + quad * 8];
#pragma unroll
        for (int mi = 0; mi < 4; mi++)
#pragma unroll
            for (int ni = 0; ni < 4; ni++)
                acc[mi][ni] = __builtin_amdgcn_mfma_f32_16x16x32_f16(af[mi], bf[ni], acc[mi][ni], 0, 0, 0);
        __syncthreads();
    }
#pragma unroll
    for (int mi = 0; mi < 4; mi++)
#pragma unroll
        for (int ni = 0; ni < 4; ni++)
#pragma unroll
            for (int r = 0; r < 4; r++) {
                int m = m0 + wm * 64 + mi * 16 + quad * 4 + r;
                int n = n0 + wn * 64 + ni * 16 + lrow;
                C[(long)m * NG + n] = (f16)(acc[mi][ni][r] + bias[n]);
            }
}

// ---------------- phase 3: out[b][t][n] = relu(hs @ Wo + bo) (f32 out, row remap) ----------------
__launch_bounds__(256)
__global__ void gemm_hw(const f16* __restrict__ A, const f16* __restrict__ Bt,
                        const float* __restrict__ bias, float* __restrict__ out)
{
    __shared__ f16 sA[128 * 32];
    __shared__ f16 sB[128 * 32];
    const int tid = threadIdx.x;
    const int m0 = blockIdx.y * 128;
    const int n0 = blockIdx.x * 128;
    const int wave = tid >> 6, lane = tid & 63;
    const int wm = wave >> 1, wn = wave & 1;
    const int lrow = lane & 15, quad = lane >> 4;

    float4v acc[4][4];
#pragma unroll
    for (int i = 0; i < 4; i++)
#pragma unroll
        for (int j = 0; j < 4; j++) acc[i][j] = (float4v){0.f, 0.f, 0.f, 0.f};

    const int srow = tid >> 2;
    const int sk8 = (tid & 3) * 8;

    for (int k0 = 0; k0 < 512; k0 += 32) {
#pragma unroll
        for (int rr = 0; rr < 128; rr += 64) {
            const int row = rr + srow;
            *(uint4*)&sA[row * 32 + sk8] = *(const uint4*)&A[(long)(m0 + row) * 512 + k0 + sk8];
            *(uint4*)&sB[row * 32 + sk8] = *(const uint4*)&Bt[(long)(n0 + row) * 512 + k0 + sk8];
        }
        __syncthreads();
        half8 af[4], bf[4];
#pragma unroll
        for (int mi = 0; mi < 4; mi++)
            af[mi] = *(half8*)&sA[(wm * 64 + mi * 16 + lrow) * 32 + quad * 8];
#pragma unroll
        for (int ni = 0; ni < 4; ni++)
            bf[ni] = *(half8*)&sB[(wn * 64 + ni * 16 + lrow) * 32 + quad * 8];
#pragma unroll
        for (int mi = 0; mi < 4; mi++)
#pragma unroll
            for (int ni = 0; ni < 4; ni++)
                acc[mi][ni] = __builtin_amdgcn_mfma_f32_16x16x32_f16(af[mi], bf[ni], acc[mi][ni], 0, 0, 0);
        __syncthreads();
    }
#pragma unroll
    for (int mi = 0; mi < 4; mi++)
#pragma unroll
        for (int ni = 0; ni < 4; ni++)
#pragma unroll
            for (int r = 0; r < 4; r++) {
                int m = m0 + wm * 64 + mi * 16 + quad * 4 + r;   // m = t*B + b
                int n = n0 + wn * 64 + ni * 16 + lrow;
                float v = acc[mi][ni][r] + bias[n];
                v = fmaxf(v, 0.f);
                int t = m >> 5, b = m & 31;
                out[(long)b * (T_ * (long)N_) + (long)t * N_ + n] = v;
            }
}

// ---------------- phase 2: the recurrence (MFMA version) ----------------
// 32 groups (one per batch) x 8 blocks x 512 threads (8 waves). Each wave owns
// 32 gate-columns; their U columns live permanently in registers as MFMA
// B-fragments (2 N-tiles x 16 K-steps x 4 VGPR = 128 regs). Per step, h_{t-1}
// (512 f16 in LDS) is broadcast into all 16 A-rows via one conflict-free
// ds_read_b128 per K-step (4 distinct bank-disjoint addresses, broadcast to 16
// lanes each), and the full K=512 dot accumulates inside 32 MFMAs on the
// matrix pipe -- replacing 128 fdot2 + 32 bank-aliased LDS reads per thread.
// All C-rows are identical (A rows replicated), so lane<32 reg0 holds the
// per-column pre-activation directly; no cross-lane reduce needed.
// Cross-block handoff unchanged: ONE tagged u64 per h-pair, relaxed
// agent-scope atomics, parity double-buffer (same safety argument as before:
// producer overwrites slot parity p only after its block observed tag t on
// ALL slots at the top of step t).
__launch_bounds__(512, 2)
__global__ void lstm_rec(const f16* __restrict__ Ut,      // [2048 cols][512 rows] f16
                         const f16* __restrict__ xpre,    // [B][T][2048] f16
                         u64* __restrict__ hg64,          // [2][32][256] tagged h pairs
                         unsigned* __restrict__ hs32,     // [T][B][256] u32 (packed f16x2)
                         int unused)
{
    const int tid = threadIdx.x;
    const int bb = blockIdx.x & 31;   // batch
    const int s  = blockIdx.x >> 5;   // slice 0..7 (blocks of a group 32 apart -> same XCD)
    const int w    = tid >> 6;        // wave 0..7: owns block-cols [32w, 32w+32)
    const int lane = tid & 63;
    const int quad = lane >> 4;
    const int lcol = lane & 15;
    const int g0    = w >> 1;         // gate of this wave's columns
    const int ebase = (w & 1) * 32;   // e-offset within the gate

    __shared__ __align__(16) unsigned hbuf32[256];   // h_{t-1}: 512 f16 packed
    __shared__ float prelds[256];                    // h@U partial per block-col

    // ---- persistent B-fragments: U[:,gcol] for this wave's 32 columns ----
    // B layout for mfma_f32_16x16x32_f16: lane holds col = lane&15,
    // k = (lane>>4)*8 + j  -> 8 consecutive rows of one column = one uint4.
    half8 bf0[16], bf1[16];
    {
        const int e0 = ebase + lcol;
        const int e1 = ebase + 16 + lcol;
        const f16* bp0 = Ut + (long)(g0 * 512 + s * 64 + e0) * 512 + quad * 8;
        const f16* bp1 = Ut + (long)(g0 * 512 + s * 64 + e1) * 512 + quad * 8;
#pragma unroll
        for (int ks = 0; ks < 16; ks++) {
            bf0[ks] = *(const half8*)(bp0 + ks * 32);
            bf1[ks] = *(const half8*)(bp1 + ks * 32);
        }
    }

    if (tid < 256) hbuf32[tid] = 0u;   // h_{-1} = 0
    float c0 = 0.f, c1 = 0.f;          // valid for tid<32: c-state of cols s*64+2*tid{,+1}
    __syncthreads();

    // xpre pointer for gate threads: u32 covering cols {s*64+2*tid, +1} per gate
    const unsigned* xq = (const unsigned*)(xpre + (long)bb * T_ * NG + s * 64) + tid;

    for (int t = 0; t < T_; ++t) {
        // xpre prefetch for the gate threads (issued before the poll so HBM
        // latency overlaps the wait; consumed only after barrier2).
        unsigned xpp0 = 0, xpp1 = 0, xpp2 = 0, xpp3 = 0;
        if (tid < 32) {
            const long o = (long)t * 1024;     // t*NG/2 in u32 units
            xpp0 = xq[o];        // gate i
            xpp1 = xq[o + 256];  // gate f
            xpp2 = xq[o + 512];  // gate g
            xpp3 = xq[o + 768];  // gate c
        }

        // ---- acquire h_{t-1} : poll tagged data words directly ----
        if (t > 0 && tid < 256) {
            const u64* slot = hg64 + (size_t)(t & 1) * 8192 + bb * 256 + tid;
            const unsigned tag = (unsigned)t;
            u64 v;
            while ((unsigned)((v = __hip_atomic_load(slot, __ATOMIC_RELAXED,
                                                     __HIP_MEMORY_SCOPE_AGENT)) >> 32) != tag)
                __builtin_amdgcn_s_sleep(1);
            hbuf32[tid] = (unsigned)v;
        }
        __syncthreads();

        // ---- h @ U via MFMA: A = h broadcast into all 16 rows ----
        // A layout: lane needs h[32ks + quad*8 + j] -> uint4 at dword
        // 16*ks + quad*4 (4 distinct addresses, banks disjoint, broadcast).
        float4v a0 = {0.f, 0.f, 0.f, 0.f}, a1 = {0.f, 0.f, 0.f, 0.f};
        float4v a2 = {0.f, 0.f, 0.f, 0.f}, a3 = {0.f, 0.f, 0.f, 0.f};
#pragma unroll
        for (int ks = 0; ks < 16; ks += 2) {
            U4H8 av0, av1;
            av0.u = *(const uint4*)&hbuf32[ks * 16 + quad * 4];
            av1.u = *(const uint4*)&hbuf32[(ks + 1) * 16 + quad * 4];
            a0 = __builtin_amdgcn_mfma_f32_16x16x32_f16(av0.h, bf0[ks],     a0, 0, 0, 0);
            a1 = __builtin_amdgcn_mfma_f32_16x16x32_f16(av0.h, bf1[ks],     a1, 0, 0, 0);
            a2 = __builtin_amdgcn_mfma_f32_16x16x32_f16(av1.h, bf0[ks + 1], a2, 0, 0, 0);
            a3 = __builtin_amdgcn_mfma_f32_16x16x32_f16(av1.h, bf1[ks + 1], a3, 0, 0, 0);
        }
        // All C rows identical; reg0 of lanes 0..31 covers the wave's 32 cols.
        if (lane < 32)
            prelds[w * 32 + lane] = (lane < 16) ? (a0[0] + a2[0]) : (a1[0] + a3[0]);
        __syncthreads();

        // ---- gates + state update + tagged release store ----
        if (tid < 32) {
            const int c2 = 2 * tid;
            U32H2 xi_, xf_, xg_, xc_;
            xi_.u = xpp0; xf_.u = xpp1; xg_.u = xpp2; xc_.u = xpp3;
            float pi0 = prelds[c2]       + (float)xi_.h[0], pi1 = prelds[c2 + 1]       + (float)xi_.h[1];
            float pf0 = prelds[64 + c2]  + (float)xf_.h[0], pf1 = prelds[64 + c2 + 1]  + (float)xf_.h[1];
            float pg0 = prelds[128 + c2] + (float)xg_.h[0], pg1 = prelds[128 + c2 + 1] + (float)xg_.h[1];
            float pc0 = prelds[192 + c2] + (float)xc_.h[0], pc1 = prelds[192 + c2 + 1] + (float)xc_.h[1];
            float gi0 = 1.f / (1.f + __expf(-pi0)), gi1 = 1.f / (1.f + __expf(-pi1));
            float gf0 = 1.f / (1.f + __expf(-pf0)), gf1 = 1.f / (1.f + __expf(-pf1));
            float gg0 = 1.f / (1.f + __expf(-pg0)), gg1 = 1.f / (1.f + __expf(-pg1));
            float ct0 = tanhf(pc0), ct1 = tanhf(pc1);
            c0 = gf0 * c0 + gi0 * ct0;
            c1 = gf1 * c1 + gi1 * ct1;
            float h0 = gg0 * tanhf(c0);
            float h1 = gg1 * tanhf(c1);
            union { f16 h[2]; unsigned u; } pk;
            pk.h[0] = (f16)h0; pk.h[1] = (f16)h1;
            u64 pv = ((u64)(unsigned)(t + 1) << 32) | (u64)pk.u;
            __hip_atomic_store(hg64 + (size_t)((t + 1) & 1) * 8192 + bb * 256 + s * 32 + tid,
                               pv, __ATOMIC_RELAXED, __HIP_MEMORY_SCOPE_AGENT);
            // history for gemm_hw: normal cached store (not on critical path)
            hs32[((long)t * B_ + bb) * 256 + s * 32 + tid] = pk.u;
        }
        // no trailing barrier: next iteration's poll + barrier provide ordering
    }
}

// ---------------- launch ----------------
extern "C" void kernel_launch(void* const* d_in, const int* in_sizes, int n_in,
                              void* d_out, int out_size, void* d_ws, size_t ws_size,
                              hipStream_t stream)
{
    const float* x  = (const float*)d_in[0];
    const float* Wi = (const float*)d_in[1];
    const float* Ui = (const float*)d_in[2];
    const float* Wf = (const float*)d_in[3];
    const float* Uf = (const float*)d_in[4];
    const float* Wg = (const float*)d_in[5];
    const float* Ug = (const float*)d_in[6];
    const float* Wc = (const float*)d_in[7];
    const float* Uc = (const float*)d_in[8];
    const float* Wo = (const float*)d_in[9];
    const float* bi = (const float*)d_in[10];
    const float* bf = (const float*)d_in[11];
    const float* bg = (const float*)d_in[12];
    const float* bc = (const float*)d_in[13];
    const float* bo = (const float*)d_in[14];

    char* ws = (char*)d_ws;
    f16*      x16   = (f16*)(ws + 0L);            // 64 MB
    f16*      xpre  = (f16*)(ws + 67108864L);     // 256 MB
    f16*      hs    = (f16*)(ws + 335544320L);    // 64 MB
    f16*      wt    = (f16*)(ws + 402653184L);    // 2 MB
    f16*      ut    = (f16*)(ws + 404750336L);    // 2 MB
    f16*      wot   = (f16*)(ws + 406847488L);    // 0.5 MB
    float*    bias  = (float*)(ws + 407371776L);  // 8 KB
    u64*      hg64  = (u64*)(ws + 407379968L);    // 128 KB tagged h exchange
    // hg64 is re-poisoned to 0xAA each call -> tag 0xAAAAAAAA never matches a
    // real t in [1,2048], so stale data cannot satisfy a poll.

    prep_cast<<<dim3(32768), dim3(256), 0, stream>>>(x, x16);
    prep_w<<<dim3(1024, 10), dim3(256), 0, stream>>>(Wi, Ui, Wf, Uf, Wg, Ug, Wc, Uc, Wo,
                                                     bi, bf, bg, bc, wt, ut, wot, bias);
    gemm_xw<<<dim3(16, 512), dim3(256), 0, stream>>>(x16, wt, bias, xpre);
    lstm_rec<<<dim3(256), dim3(512), 0, stream>>>(ut, xpre, hg64, (unsigned*)hs, 0);
    gemm_hw<<<dim3(4, 512), dim3(256), 0, stream>>>(hs, wot, bo, (float*)d_out);
}

// Round 2
// 3699.427 us; speedup vs baseline: 1.4104x; 1.2006x over previous
//
#include <hip/hip_runtime.h>
#include <stdint.h>

// Problem constants
#define B_ 32
#define T_ 2048
#define D_ 512
#define N_ 512
#define NG 2048   // 4 gates * N

typedef _Float16 f16;
typedef _Float16 half2v __attribute__((ext_vector_type(2)));
typedef _Float16 half8  __attribute__((ext_vector_type(8)));
typedef float    float4v __attribute__((ext_vector_type(4)));
typedef unsigned long long u64;

union U32H2 { unsigned u; half2v h; };
union U4H8  { uint4 u; half8 h; };
union H16U  { f16 h; unsigned short s; };

static __device__ __forceinline__ float fast_sigmoid(float x) {
    return __builtin_amdgcn_rcpf(1.f + __expf(-x));
}
static __device__ __forceinline__ float fast_tanh(float x) {
    // 1 - 2/(1+e^{2x}): correct limits at +/-inf, no clamp needed, ~1e-7 abs err
    return 1.f - 2.f * __builtin_amdgcn_rcpf(1.f + __expf(2.f * x));
}

// ---------------- prep: cast x (f32) -> f16 ----------------
__global__ void prep_cast(const float* __restrict__ x, f16* __restrict__ x16) {
    long i = ((long)blockIdx.x * 256 + threadIdx.x) * 4;
    float4 v = *(const float4*)(x + i);
    union { f16 h[4]; uint2 u; } pk;
    pk.h[0] = (f16)v.x; pk.h[1] = (f16)v.y; pk.h[2] = (f16)v.z; pk.h[3] = (f16)v.w;
    *(uint2*)(x16 + i) = pk.u;
}

// ---------------- prep: transpose+cast weights, biases ----------------
__global__ void prep_w(const float* __restrict__ Wi, const float* __restrict__ Ui,
                       const float* __restrict__ Wf, const float* __restrict__ Uf,
                       const float* __restrict__ Wg, const float* __restrict__ Ug,
                       const float* __restrict__ Wc, const float* __restrict__ Uc,
                       const float* __restrict__ Wo,
                       const float* __restrict__ bi, const float* __restrict__ bff,
                       const float* __restrict__ bg, const float* __restrict__ bc,
                       f16* __restrict__ wt, f16* __restrict__ ut,
                       f16* __restrict__ wot, float* __restrict__ bias)
{
    const int y = blockIdx.y;
    const int e = blockIdx.x * 256 + threadIdx.x;   // 0..262143
    if (y < 4) {
        const float* src = (y == 0) ? Wi : (y == 1) ? Wf : (y == 2) ? Wg : Wc;
        int col = e >> 9, d = e & 511;
        wt[(long)y * 512 * 512 + e] = (f16)src[(long)d * 512 + col];   // wt[(g*512+col)][d]
    } else if (y < 8) {
        const float* src = (y == 4) ? Ui : (y == 5) ? Uf : (y == 6) ? Ug : Uc;
        int col = e >> 9, d = e & 511;
        ut[(long)(y - 4) * 512 * 512 + e] = (f16)src[(long)d * 512 + col];
    } else if (y == 8) {
        int col = e >> 9, d = e & 511;
        wot[e] = (f16)Wo[(long)d * 512 + col];
    } else {
        if (e < 2048) {
            const float* bsrc = (e < 512) ? bi : (e < 1024) ? bff : (e < 1536) ? bg : bc;
            bias[e] = bsrc[e & 511];
        }
    }
}

// ---------------- phase 1: xpre[b][t][2048] = x @ [Wi|Wf|Wg|Wc] + bias (f16 out) ----------------
__launch_bounds__(256)
__global__ void gemm_xw(const f16* __restrict__ A, const f16* __restrict__ Bt,
                        const float* __restrict__ bias, f16* __restrict__ C)
{
    __shared__ f16 sA[128 * 32];
    __shared__ f16 sB[128 * 32];
    const int tid = threadIdx.x;
    const int m0 = blockIdx.y * 128;
    const int n0 = blockIdx.x * 128;
    const int wave = tid >> 6, lane = tid & 63;
    const int wm = wave >> 1, wn = wave & 1;
    const int lrow = lane & 15, quad = lane >> 4;

    float4v acc[4][4];
#pragma unroll
    for (int i = 0; i < 4; i++)
#pragma unroll
        for (int j = 0; j < 4; j++) acc[i][j] = (float4v){0.f, 0.f, 0.f, 0.f};

    const int srow = tid >> 2;        // 0..63
    const int sk8 = (tid & 3) * 8;    // 0,8,16,24

    for (int k0 = 0; k0 < 512; k0 += 32) {
#pragma unroll
        for (int rr = 0; rr < 128; rr += 64) {
            const int row = rr + srow;
            *(uint4*)&sA[row * 32 + sk8] = *(const uint4*)&A[(long)(m0 + row) * 512 + k0 + sk8];
            *(uint4*)&sB[row * 32 + sk8] = *(const uint4*)&Bt[(long)(n0 + row) * 512 + k0 + sk8];
        }
        __syncthreads();
        half8 af[4], bf[4];
#pragma unroll
        for (int mi = 0; mi < 4; mi++)
            af[mi] = *(half8*)&sA[(wm * 64 + mi * 16 + lrow) * 32 + quad * 8];
#pragma unroll
        for (int ni = 0; ni < 4; ni++)
            bf[ni] = *(half8*)&sB[(wn * 64 + ni * 16 + lrow) * 32 + quad * 8];
#pragma unroll
        for (int mi = 0; mi < 4; mi++)
#pragma unroll
            for (int ni = 0; ni < 4; ni++)
                acc[mi][ni] = __builtin_amdgcn_mfma_f32_16x16x32_f16(af[mi], bf[ni], acc[mi][ni], 0, 0, 0);
        __syncthreads();
    }
#pragma unroll
    for (int mi = 0; mi < 4; mi++)
#pragma unroll
        for (int ni = 0; ni < 4; ni++)
#pragma unroll
            for (int r = 0; r < 4; r++) {
                int m = m0 + wm * 64 + mi * 16 + quad * 4 + r;
                int n = n0 + wn * 64 + ni * 16 + lrow;
                C[(long)m * NG + n] = (f16)(acc[mi][ni][r] + bias[n]);
            }
}

// ---------------- phase 3: out[b][t][n] = relu(hs @ Wo + bo) (f32 out, row remap) ----------------
__launch_bounds__(256)
__global__ void gemm_hw(const f16* __restrict__ A, const f16* __restrict__ Bt,
                        const float* __restrict__ bias, float* __restrict__ out)
{
    __shared__ f16 sA[128 * 32];
    __shared__ f16 sB[128 * 32];
    const int tid = threadIdx.x;
    const int m0 = blockIdx.y * 128;
    const int n0 = blockIdx.x * 128;
    const int wave = tid >> 6, lane = tid & 63;
    const int wm = wave >> 1, wn = wave & 1;
    const int lrow = lane & 15, quad = lane >> 4;

    float4v acc[4][4];
#pragma unroll
    for (int i = 0; i < 4; i++)
#pragma unroll
        for (int j = 0; j < 4; j++) acc[i][j] = (float4v){0.f, 0.f, 0.f, 0.f};

    const int srow = tid >> 2;
    const int sk8 = (tid & 3) * 8;

    for (int k0 = 0; k0 < 512; k0 += 32) {
#pragma unroll
        for (int rr = 0; rr < 128; rr += 64) {
            const int row = rr + srow;
            *(uint4*)&sA[row * 32 + sk8] = *(const uint4*)&A[(long)(m0 + row) * 512 + k0 + sk8];
            *(uint4*)&sB[row * 32 + sk8] = *(const uint4*)&Bt[(long)(n0 + row) * 512 + k0 + sk8];
        }
        __syncthreads();
        half8 af[4], bf[4];
#pragma unroll
        for (int mi = 0; mi < 4; mi++)
            af[mi] = *(half8*)&sA[(wm * 64 + mi * 16 + lrow) * 32 + quad * 8];
#pragma unroll
        for (int ni = 0; ni < 4; ni++)
            bf[ni] = *(half8*)&sB[(wn * 64 + ni * 16 + lrow) * 32 + quad * 8];
#pragma unroll
        for (int mi = 0; mi < 4; mi++)
#pragma unroll
            for (int ni = 0; ni < 4; ni++)
                acc[mi][ni] = __builtin_amdgcn_mfma_f32_16x16x32_f16(af[mi], bf[ni], acc[mi][ni], 0, 0, 0);
        __syncthreads();
    }
#pragma unroll
    for (int mi = 0; mi < 4; mi++)
#pragma unroll
        for (int ni = 0; ni < 4; ni++)
#pragma unroll
            for (int r = 0; r < 4; r++) {
                int m = m0 + wm * 64 + mi * 16 + quad * 4 + r;   // m = t*B + b
                int n = n0 + wn * 64 + ni * 16 + lrow;
                float v = acc[mi][ni][r] + bias[n];
                v = fmaxf(v, 0.f);
                int t = m >> 5, b = m & 31;
                out[(long)b * (T_ * (long)N_) + (long)t * N_ + n] = v;
            }
}

// ---------------- phase 2: the recurrence (MFMA + pipelined xpre) ----------------
// Same structure/comm as before (tagged u64 slots, relaxed agent atomics,
// parity double-buffer). Changes this round:
//  (1) xpre loads are issued AFTER the poll (for step t+1, consumed next
//      iteration). Previously they were issued before the poll, and the poll's
//      vmcnt(0) (needed for its own atomic load result) force-drained the
//      ~900-cycle HBM load every step -- a serial HBM round trip on the
//      critical path.
//  (2) Gate math runs on 64 lanes (1 column each) instead of 32 (2 cols each),
//      with exp-form tanh + v_rcp instead of library tanhf + exact division.
//      h-pairs are repacked via two __shfl.
__launch_bounds__(512, 2)
__global__ void lstm_rec(const f16* __restrict__ Ut,      // [2048 cols][512 rows] f16
                         const f16* __restrict__ xpre,    // [B][T][2048] f16
                         u64* __restrict__ hg64,          // [2][32][256] tagged h pairs
                         unsigned* __restrict__ hs32,     // [T][B][256] u32 (packed f16x2)
                         int unused)
{
    const int tid = threadIdx.x;
    const int bb = blockIdx.x & 31;   // batch
    const int s  = blockIdx.x >> 5;   // slice 0..7 (blocks of a group 32 apart -> same XCD)
    const int w    = tid >> 6;        // wave 0..7: owns block-cols [32w, 32w+32)
    const int lane = tid & 63;
    const int quad = lane >> 4;
    const int lcol = lane & 15;
    const int g0    = w >> 1;         // gate of this wave's columns
    const int ebase = (w & 1) * 32;   // e-offset within the gate

    __shared__ __align__(16) unsigned hbuf32[256];   // h_{t-1}: 512 f16 packed
    __shared__ float prelds[256];                    // h@U partial per block-col

    // ---- persistent B-fragments: U[:,gcol] for this wave's 32 columns ----
    half8 bf0[16], bf1[16];
    {
        const int e0 = ebase + lcol;
        const int e1 = ebase + 16 + lcol;
        const f16* bp0 = Ut + (long)(g0 * 512 + s * 64 + e0) * 512 + quad * 8;
        const f16* bp1 = Ut + (long)(g0 * 512 + s * 64 + e1) * 512 + quad * 8;
#pragma unroll
        for (int ks = 0; ks < 16; ks++) {
            bf0[ks] = *(const half8*)(bp0 + ks * 32);
            bf1[ks] = *(const half8*)(bp1 + ks * 32);
        }
    }

    if (tid < 256) hbuf32[tid] = 0u;   // h_{-1} = 0
    float cst = 0.f;                   // valid for tid<64: c-state of col s*64+tid
    __syncthreads();

    // xpre base for gate lanes: column s*64 + lane, per-gate stride 512 f16
    const f16* xb = xpre + (long)bb * T_ * NG + s * 64 + tid;   // valid use: tid<64

    // preload xpre for t=0 (no poll before it, so no forced drain)
    f16 xc_i = (f16)0, xc_f = (f16)0, xc_g = (f16)0, xc_c = (f16)0;
    if (tid < 64) {
        xc_i = xb[0]; xc_f = xb[512]; xc_g = xb[1024]; xc_c = xb[1536];
    }

    for (int t = 0; t < T_; ++t) {
        // ---- acquire h_{t-1} : poll tagged data words directly ----
        if (t > 0 && tid < 256) {
            const u64* slot = hg64 + (size_t)(t & 1) * 8192 + bb * 256 + tid;
            const unsigned tag = (unsigned)t;
            u64 v;
            while ((unsigned)((v = __hip_atomic_load(slot, __ATOMIC_RELAXED,
                                                     __HIP_MEMORY_SCOPE_AGENT)) >> 32) != tag)
                __builtin_amdgcn_s_sleep(1);
            hbuf32[tid] = (unsigned)v;
        }
        __syncthreads();

        // ---- issue xpre loads for step t+1 (consumed next iteration's gate
        // phase; slack to the next vmcnt(0) (next poll) covers HBM latency) ----
        f16 xn_i = (f16)0, xn_f = (f16)0, xn_g = (f16)0, xn_c = (f16)0;
        if (t < T_ - 1 && tid < 64) {
            const f16* p = xb + (long)(t + 1) * NG;
            xn_i = p[0]; xn_f = p[512]; xn_g = p[1024]; xn_c = p[1536];
        }

        // ---- h @ U via MFMA: A = h broadcast into all 16 rows ----
        float4v a0 = {0.f, 0.f, 0.f, 0.f}, a1 = {0.f, 0.f, 0.f, 0.f};
        float4v a2 = {0.f, 0.f, 0.f, 0.f}, a3 = {0.f, 0.f, 0.f, 0.f};
#pragma unroll
        for (int ks = 0; ks < 16; ks += 2) {
            U4H8 av0, av1;
            av0.u = *(const uint4*)&hbuf32[ks * 16 + quad * 4];
            av1.u = *(const uint4*)&hbuf32[(ks + 1) * 16 + quad * 4];
            a0 = __builtin_amdgcn_mfma_f32_16x16x32_f16(av0.h, bf0[ks],     a0, 0, 0, 0);
            a1 = __builtin_amdgcn_mfma_f32_16x16x32_f16(av0.h, bf1[ks],     a1, 0, 0, 0);
            a2 = __builtin_amdgcn_mfma_f32_16x16x32_f16(av1.h, bf0[ks + 1], a2, 0, 0, 0);
            a3 = __builtin_amdgcn_mfma_f32_16x16x32_f16(av1.h, bf1[ks + 1], a3, 0, 0, 0);
        }
        // All C rows identical; reg0 of lanes 0..31 covers the wave's 32 cols.
        if (lane < 32)
            prelds[w * 32 + lane] = (lane < 16) ? (a0[0] + a2[0]) : (a1[0] + a3[0]);
        __syncthreads();

        // ---- gates: 64 lanes, one column each ----
        if (tid < 64) {
            float pre_i = prelds[tid]       + (float)xc_i;
            float pre_f = prelds[64 + tid]  + (float)xc_f;
            float pre_g = prelds[128 + tid] + (float)xc_g;
            float pre_c = prelds[192 + tid] + (float)xc_c;
            float gi = fast_sigmoid(pre_i);
            float gf = fast_sigmoid(pre_f);
            float gg = fast_sigmoid(pre_g);
            float ct = fast_tanh(pre_c);
            cst = gf * cst + gi * ct;
            float h = gg * fast_tanh(cst);

            // pack pairs: lane j (<32) collects h from lanes 2j, 2j+1
            H16U cv; cv.h = (f16)h;
            unsigned hx = (unsigned)cv.s;
            unsigned lo = __shfl(hx, 2 * lane);
            unsigned hi = __shfl(hx, 2 * lane + 1);
            if (lane < 32) {
                unsigned pk = lo | (hi << 16);
                u64 pv = ((u64)(unsigned)(t + 1) << 32) | (u64)pk;
                __hip_atomic_store(hg64 + (size_t)((t + 1) & 1) * 8192 + bb * 256 + s * 32 + lane,
                                   pv, __ATOMIC_RELAXED, __HIP_MEMORY_SCOPE_AGENT);
                // history for gemm_hw: normal cached store (not on critical path)
                hs32[((long)t * B_ + bb) * 256 + s * 32 + lane] = pk;
            }
        }
        // rotate xpre pipeline registers
        xc_i = xn_i; xc_f = xn_f; xc_g = xn_g; xc_c = xn_c;
        // no trailing barrier: next iteration's poll + barrier provide ordering
    }
}

// ---------------- launch ----------------
extern "C" void kernel_launch(void* const* d_in, const int* in_sizes, int n_in,
                              void* d_out, int out_size, void* d_ws, size_t ws_size,
                              hipStream_t stream)
{
    const float* x  = (const float*)d_in[0];
    const float* Wi = (const float*)d_in[1];
    const float* Ui = (const float*)d_in[2];
    const float* Wf = (const float*)d_in[3];
    const float* Uf = (const float*)d_in[4];
    const float* Wg = (const float*)d_in[5];
    const float* Ug = (const float*)d_in[6];
    const float* Wc = (const float*)d_in[7];
    const float* Uc = (const float*)d_in[8];
    const float* Wo = (const float*)d_in[9];
    const float* bi = (const float*)d_in[10];
    const float* bf = (const float*)d_in[11];
    const float* bg = (const float*)d_in[12];
    const float* bc = (const float*)d_in[13];
    const float* bo = (const float*)d_in[14];

    char* ws = (char*)d_ws;
    f16*      x16   = (f16*)(ws + 0L);            // 64 MB
    f16*      xpre  = (f16*)(ws + 67108864L);     // 256 MB
    f16*      hs    = (f16*)(ws + 335544320L);    // 64 MB
    f16*      wt    = (f16*)(ws + 402653184L);    // 2 MB
    f16*      ut    = (f16*)(ws + 404750336L);    // 2 MB
    f16*      wot   = (f16*)(ws + 406847488L);    // 0.5 MB
    float*    bias  = (float*)(ws + 407371776L);  // 8 KB
    u64*      hg64  = (u64*)(ws + 407379968L);    // 128 KB tagged h exchange
    // hg64 is re-poisoned to 0xAA each call -> tag 0xAAAAAAAA never matches a
    // real t in [1,2048], so stale data cannot satisfy a poll.

    prep_cast<<<dim3(32768), dim3(256), 0, stream>>>(x, x16);
    prep_w<<<dim3(1024, 10), dim3(256), 0, stream>>>(Wi, Ui, Wf, Uf, Wg, Ug, Wc, Uc, Wo,
                                                     bi, bf, bg, bc, wt, ut, wot, bias);
    gemm_xw<<<dim3(16, 512), dim3(256), 0, stream>>>(x16, wt, bias, xpre);
    lstm_rec<<<dim3(256), dim3(512), 0, stream>>>(ut, xpre, hg64, (unsigned*)hs, 0);
    gemm_hw<<<dim3(4, 512), dim3(256), 0, stream>>>(hs, wot, bo, (float*)d_out);
}